// Round 3
// baseline (169.122 us; speedup 1.0000x reference)
//
#include <hip/hip_runtime.h>
#include <math.h>

// N=8192, M=64, K=256, D=16
#define M_SUB 64
#define K_CODES 256
#define D_DIM 16
#define ROW_F 1024            // floats per vecs/out row = M*D
#define THRGAP 0.0078125f     // top-2 gap below this -> exact fp64 fixup

typedef __attribute__((ext_vector_type(8))) short short8;
typedef __attribute__((ext_vector_type(4))) float f32x4;

// ---- bf16 RNE split helpers (bit math, branchless) ----
__device__ inline unsigned bfr(float x) {           // f32 -> bf16 bits (RNE)
    unsigned u = __builtin_bit_cast(unsigned, x);
    return (u + 0x7FFFu + ((u >> 16) & 1u)) >> 16;
}
__device__ inline float bff(unsigned h) { return __builtin_bit_cast(float, h << 16); }

// ---- DPP cross-lane (VALU-only) reduce helpers ----
template <int C> __device__ inline float dppf(float x) {
    return __builtin_bit_cast(float,
        __builtin_amdgcn_update_dpp(0, __builtin_bit_cast(int, x), C, 0xF, 0xF, true));
}
template <int C> __device__ inline int dppi(int x) {
    return __builtin_amdgcn_update_dpp(0, x, C, 0xF, 0xF, true);
}
// merge (best, best2, bestk) with DPP partner; combining tree over 16-lane rows
template <int C> __device__ inline void merge3(float& b, float& b2, int& bk) {
    float bo = dppf<C>(b), b2o = dppf<C>(b2);
    int   ko = dppi<C>(bk);
    b2 = fmaxf(fmaxf(b2, b2o), fminf(b, bo));
    if (bo > b) { b = bo; bk = ko; }
}

// ===================== kernel 1: MFMA scores + argmax =====================
// Layout assumptions (centralized here; permute if absmax fails):
//  A-frag (16x32): lane l -> row l&15, K-slots 8*(l>>4)+{0..7} (short8, j ascending)
//  B-frag (32x16): lane l -> col l&15, K-slots 8*(l>>4)+{0..7}
//  C/D   (m89-verified): col = lane&15, row = (lane>>4)*4 + reg
__global__ __launch_bounds__(256, 4) void pq_mfma_kernel(
    const float* __restrict__ vecs, const float* __restrict__ cb,
    float* __restrict__ out, unsigned* __restrict__ meta, unsigned cap)
{
    const int m   = blockIdx.y;
    const int nb  = blockIdx.x * 512;       // 512 rows per block
    const int tid = threadIdx.x;
    const int w    = tid >> 6;
    const int lane = tid & 63;
    const int lr   = lane & 15;             // A-row / B-col / D-col selector
    const int lg   = lane >> 4;             // K-group / D-row-group

    // LDS: codebook split to bf16 hi/lo. Per code: 4 chunks x 8 shorts
    // [ch d0-7 | ch d8-15 | cl d0-7 | cl d8-15], stride 40 shorts (80 B, 16B-aligned,
    // 2-way-max bank aliasing = free).
    __shared__ short BLDS[K_CODES * 40];
    __shared__ float NC2[K_CODES];          // -||c||^2 (fp32)

    { // stage + convert: thread t handles code t
        const float* cp = cb + ((size_t)m * K_CODES + tid) * D_DIM;
        float f[16];
        #pragma unroll
        for (int q = 0; q < 4; ++q) {
            float4 t4 = ((const float4*)cp)[q];
            f[q*4+0] = t4.x; f[q*4+1] = t4.y; f[q*4+2] = t4.z; f[q*4+3] = t4.w;
        }
        float c2 = 0.f;
        #pragma unroll
        for (int d = 0; d < 16; ++d) c2 = fmaf(f[d], f[d], c2);
        NC2[tid] = -c2;
        short hi[16], lo[16];
        #pragma unroll
        for (int d = 0; d < 16; ++d) {
            unsigned h = bfr(f[d]);
            hi[d] = (short)h;
            lo[d] = (short)bfr(f[d] - bff(h));
        }
        short* base = &BLDS[tid * 40];
        short8 v0 = { hi[0],hi[1],hi[2],hi[3],hi[4],hi[5],hi[6],hi[7] };
        short8 v1 = { hi[8],hi[9],hi[10],hi[11],hi[12],hi[13],hi[14],hi[15] };
        short8 v2 = { lo[0],lo[1],lo[2],lo[3],lo[4],lo[5],lo[6],lo[7] };
        short8 v3 = { lo[8],lo[9],lo[10],lo[11],lo[12],lo[13],lo[14],lo[15] };
        *(short8*)&base[0]  = v0; *(short8*)&base[8]  = v1;
        *(short8*)&base[16] = v2; *(short8*)&base[24] = v3;
    }
    __syncthreads();

    // hoist -c2 for this lane's 16 columns (k = kt*16 + lr)
    float nc2v[16];
    #pragma unroll
    for (int kt = 0; kt < 16; ++kt) nc2v[kt] = NC2[kt * 16 + lr];

    unsigned* cnt = meta;
    unsigned* list = meta + 1;

    #pragma unroll 1
    for (int i = 0; i < 8; ++i) {           // 8 tiles of 16 rows per wave
        const int n0 = nb + w * 128 + i * 16;

        // ---- A fragments: row n0+lr, d-chunk (lg&1)*8, pre-scaled by 2, split hi/lo
        const float* vp = vecs + (size_t)(n0 + lr) * ROW_F + m * D_DIM + (lg & 1) * 8;
        float f[8];
        {
            float4 a = ((const float4*)vp)[0], b = ((const float4*)vp)[1];
            f[0]=2.f*a.x; f[1]=2.f*a.y; f[2]=2.f*a.z; f[3]=2.f*a.w;
            f[4]=2.f*b.x; f[5]=2.f*b.y; f[6]=2.f*b.z; f[7]=2.f*b.w;
        }
        short hi[8], lo[8];
        #pragma unroll
        for (int e = 0; e < 8; ++e) {
            unsigned h = bfr(f[e]);
            hi[e] = (short)h;
            lo[e] = (short)bfr(f[e] - bff(h));
        }
        short8 H = { hi[0],hi[1],hi[2],hi[3],hi[4],hi[5],hi[6],hi[7] };
        short8 L = { lo[0],lo[1],lo[2],lo[3],lo[4],lo[5],lo[6],lo[7] };
        const bool hiSide = (lg < 2);
        short8 A1 = hiSide ? H : L;          // [2v_hi | 2v_lo]
        short8 A2 = hiSide ? L : H;          // [2v_lo | 2v_hi]

        // ---- scores: acc[kt] = (2v)·c - c2, via 2 MFMAs per k-tile
        f32x4 acc[16];
        #pragma unroll
        for (int kt = 0; kt < 16; ++kt) {
            short8 B = *(const short8*)&BLDS[(kt * 16 + lr) * 40 + lg * 8]; // [ch|cl]
            float nv = nc2v[kt];
            f32x4 c0 = { nv, nv, nv, nv };
            c0 = __builtin_amdgcn_mfma_f32_16x16x32_bf16(A1, B, c0, 0, 0, 0);
            c0 = __builtin_amdgcn_mfma_f32_16x16x32_bf16(A2, B, c0, 0, 0, 0);
            acc[kt] = c0;
        }

        // ---- per-row argmax + top-2 gap (in-register, DPP reduce over 16 lanes)
        int kp0 = 0, kp1 = 0, kp2 = 0, kp3 = 0;
        #pragma unroll
        for (int p = 0; p < 4; ++p) {        // row = lg*4 + p
            float b = -INFINITY, b2 = -INFINITY;
            int bk = 0;
            #pragma unroll
            for (int kt = 0; kt < 16; ++kt) {  // k ascending within lane
                float v = acc[kt][p];
                b2 = fmaxf(b2, fminf(v, b));
                if (v > b) { b = v; bk = kt * 16 + lr; }
            }
            merge3<0xB1>(b, b2, bk);         // quad_perm xor1
            merge3<0x4E>(b, b2, bk);         // quad_perm xor2
            merge3<0x141>(b, b2, bk);        // row_half_mirror
            merge3<0x140>(b, b2, bk);        // row_mirror -> full 16-lane row
            if (p == 0) kp0 = bk; else if (p == 1) kp1 = bk;
            else if (p == 2) kp2 = bk; else kp3 = bk;
            if (lr == 0 && !(b - b2 > THRGAP)) {   // near-tie (or NaN) -> exact pass
                unsigned idx = atomicAdd(cnt, 1u);
                if (idx < cap) list[idx] = ((unsigned)(n0 + lg * 4 + p) << 6) | (unsigned)m;
            }
        }

        // ---- write output: lane writes row n0+(lane>>2), chunk lane&3
        int psel = (lane >> 2) & 3;
        int t0 = (psel & 1) ? kp1 : kp0;
        int t1 = (psel & 1) ? kp3 : kp2;
        int kwin = (psel & 2) ? t1 : t0;
        const float4* src = (const float4*)(cb + ((size_t)m * K_CODES + kwin) * D_DIM);
        float4* dst = (float4*)(out + (size_t)(n0 + (lane >> 2)) * ROW_F + m * D_DIM);
        dst[lane & 3] = src[lane & 3];
    }
}

// ===================== kernel 2: exact fp64 fixup (wave per entry) ===========
__global__ __launch_bounds__(256) void pq_fixup_kernel(
    const float* __restrict__ vecs, const float* __restrict__ cb,
    float* __restrict__ out, const unsigned* __restrict__ meta, unsigned cap)
{
    unsigned cnt = meta[0];
    if (cnt > cap) cnt = cap;
    const unsigned nw  = (gridDim.x * blockDim.x) >> 6;
    const unsigned wid = (blockIdx.x * blockDim.x + threadIdx.x) >> 6;
    const int lane = threadIdx.x & 63;

    for (unsigned e = wid; e < cnt; e += nw) {
        unsigned ent = meta[1 + e];
        const int n = (int)(ent >> 6), m = (int)(ent & 63u);
        const float* vrow = vecs + (size_t)n * ROW_F + m * D_DIM;
        double vd[16];
        #pragma unroll
        for (int d = 0; d < 16; ++d) vd[d] = (double)vrow[d];
        double bs = -1e300; int bi = 0;
        #pragma unroll
        for (int j = 0; j < 4; ++j) {        // lane's codes k = lane*4+j, ascending
            int k = lane * 4 + j;
            const float* cp = cb + ((size_t)m * K_CODES + k) * D_DIM;
            double vc = 0.0, c2 = 0.0;
            #pragma unroll
            for (int d = 0; d < 16; ++d) {
                double cd = (double)cp[d];
                vc = fma(vd[d], cd, vc);
                c2 = fma(cd, cd, c2);
            }
            double s = 2.0 * vc - c2;
            if (s > bs) { bs = s; bi = k; }
        }
        #pragma unroll
        for (int off = 32; off; off >>= 1) { // first-index tie-break across lanes
            double so = __shfl_xor(bs, off, 64);
            int    ko = __shfl_xor(bi, off, 64);
            if (so > bs || (so == bs && ko < bi)) { bs = so; bi = ko; }
        }
        if (lane < 4) {
            const float4* src = (const float4*)(cb + ((size_t)m * K_CODES + bi) * D_DIM);
            float4* dst = (float4*)(out + (size_t)n * ROW_F + m * D_DIM);
            dst[lane] = src[lane];
        }
    }
}

extern "C" void kernel_launch(void* const* d_in, const int* in_sizes, int n_in,
                              void* d_out, int out_size, void* d_ws, size_t ws_size,
                              hipStream_t stream) {
    const float* vecs = (const float*)d_in[0];
    const float* cb   = (const float*)d_in[1];
    float* out        = (float*)d_out;
    unsigned* meta    = (unsigned*)d_ws;
    unsigned cap      = (unsigned)(ws_size / 4) - 16;

    hipMemsetAsync(meta, 0, 4, stream);                       // zero append counter
    pq_mfma_kernel<<<dim3(16, 64), 256, 0, stream>>>(vecs, cb, out, meta, cap);
    pq_fixup_kernel<<<256, 256, 0, stream>>>(vecs, cb, out, meta, cap);
}

// Round 4
// 66.911 us; speedup vs baseline: 2.5276x; 2.5276x over previous
//
#include <hip/hip_runtime.h>
#include <math.h>

// N=8192, M=64, K=256, D=16
#define M_SUB 64
#define K_CODES 256
#define D_DIM 16
#define ROW_F 1024            // floats per vecs/out row
#define THRGAP 0.0078125f     // top-2 gap below this -> exact fp64 fixup
#define YS 8                  // m-groups in grid.y
#define MPB (M_SUB / YS)      // 8 m per block
#define NR 64                 // rows per block (4 waves x 16)

typedef __attribute__((ext_vector_type(8))) short short8;
typedef __attribute__((ext_vector_type(4))) float f32x4;

// ---- bf16 RNE split helpers ----
__device__ inline unsigned bfr(float x) {
    unsigned u = __builtin_bit_cast(unsigned, x);
    return (u + 0x7FFFu + ((u >> 16) & 1u)) >> 16;
}
__device__ inline float bff(unsigned h) { return __builtin_bit_cast(float, h << 16); }

// ---- DPP cross-lane helpers (16-lane-row reductions; proven in R3) ----
template <int C> __device__ inline float dppf(float x) {
    return __builtin_bit_cast(float,
        __builtin_amdgcn_update_dpp(0, __builtin_bit_cast(int, x), C, 0xF, 0xF, true));
}
template <int C> __device__ inline int dppi(int x) {
    return __builtin_amdgcn_update_dpp(0, x, C, 0xF, 0xF, true);
}

// ===================== kernel 1: MFMA scores + argmax =====================
// Fragment roles identical to the PASSING R3 kernel:
//  A lane l -> row l&15, K-slots by lg=l>>4: [2v_hi d0-7 | 2v_hi d8-15 | 2v_lo d0-7 | 2v_lo d8-15]
//  B lane l -> col l&15 (code), same K-slot split [ch|ch|cl|cl]
//  D (m89): col = lane&15, row = (lane>>4)*4 + reg
__global__ __launch_bounds__(256, 4) void pq_mfma_kernel(
    const float* __restrict__ vecs, const float* __restrict__ cb,
    float* __restrict__ out, unsigned* __restrict__ meta, unsigned cap)
{
    const int m0  = blockIdx.y * MPB;
    const int nb  = blockIdx.x * NR;
    const int tid = threadIdx.x;
    const int w    = tid >> 6;
    const int lane = tid & 63;
    const int lr   = lane & 15;
    const int lg   = lane >> 4;

    // Per code: [ch d0-7 | ch d8-15 | cl d0-7 | cl d8-15], stride 40 shorts (80 B).
    __shared__ short BLDS[K_CODES * 40];
    __shared__ float NC2[K_CODES];

    unsigned* cnt  = meta;
    unsigned* list = meta + 1;

    const int rowA = nb + w * 16 + lr;   // A-row this lane loads
    const float* vbaseA = vecs + (size_t)rowA * ROW_F + (lg & 1) * 8;

    #pragma unroll 1
    for (int mi = 0; mi < MPB; ++mi) {
        const int m = m0 + mi;
        __syncthreads();                 // previous slice fully consumed
        { // ---- stage code `tid` of slice m (contiguous 64 B/thread from L2) ----
            const float* cp = cb + ((size_t)m * K_CODES + tid) * D_DIM;
            float f[16];
            #pragma unroll
            for (int q = 0; q < 4; ++q) {
                float4 t4 = ((const float4*)cp)[q];
                f[q*4+0] = t4.x; f[q*4+1] = t4.y; f[q*4+2] = t4.z; f[q*4+3] = t4.w;
            }
            float c2 = 0.f;
            #pragma unroll
            for (int d = 0; d < 16; ++d) c2 = fmaf(f[d], f[d], c2);
            NC2[tid] = -c2;
            short hi[16], lo[16];
            #pragma unroll
            for (int d = 0; d < 16; ++d) {
                unsigned h = bfr(f[d]);
                hi[d] = (short)h;
                lo[d] = (short)bfr(f[d] - bff(h));
            }
            short* base = &BLDS[tid * 40];
            short8 v0 = { hi[0],hi[1],hi[2],hi[3],hi[4],hi[5],hi[6],hi[7] };
            short8 v1 = { hi[8],hi[9],hi[10],hi[11],hi[12],hi[13],hi[14],hi[15] };
            short8 v2 = { lo[0],lo[1],lo[2],lo[3],lo[4],lo[5],lo[6],lo[7] };
            short8 v3 = { lo[8],lo[9],lo[10],lo[11],lo[12],lo[13],lo[14],lo[15] };
            *(short8*)&base[0]  = v0; *(short8*)&base[8]  = v1;
            *(short8*)&base[16] = v2; *(short8*)&base[24] = v3;
        }
        __syncthreads();

        // ---- A fragments (contiguous 32 B/lane; block's columns are a 512 B run) ----
        const float* vp = vbaseA + m * D_DIM;
        float f[8];
        {
            float4 a = ((const float4*)vp)[0], b4 = ((const float4*)vp)[1];
            f[0]=2.f*a.x; f[1]=2.f*a.y; f[2]=2.f*a.z; f[3]=2.f*a.w;
            f[4]=2.f*b4.x; f[5]=2.f*b4.y; f[6]=2.f*b4.z; f[7]=2.f*b4.w;
        }
        short hi[8], lo[8];
        #pragma unroll
        for (int e = 0; e < 8; ++e) {
            unsigned h = bfr(f[e]);
            hi[e] = (short)h;
            lo[e] = (short)bfr(f[e] - bff(h));
        }
        short8 H = { hi[0],hi[1],hi[2],hi[3],hi[4],hi[5],hi[6],hi[7] };
        short8 L = { lo[0],lo[1],lo[2],lo[3],lo[4],lo[5],lo[6],lo[7] };
        const bool hiSide = (lg < 2);
        short8 A1 = hiSide ? H : L;
        short8 A2 = hiSide ? L : H;

        // ---- scores: acc[kt][p] = (2v)·c - ||c||^2 (exact-split bf16 MFMA, as R3) ----
        f32x4 acc[16];
        #pragma unroll
        for (int kt = 0; kt < 16; ++kt) {
            short8 B = *(const short8*)&BLDS[(kt * 16 + lr) * 40 + lg * 8];
            float nv = NC2[kt * 16 + lr];
            f32x4 c0 = { nv, nv, nv, nv };
            c0 = __builtin_amdgcn_mfma_f32_16x16x32_bf16(A1, B, c0, 0, 0, 0);
            c0 = __builtin_amdgcn_mfma_f32_16x16x32_bf16(A2, B, c0, 0, 0, 0);
            acc[kt] = c0;
        }

        // ---- argmax: fmax tree -> DPP max -> candidate count vs (b - THRGAP) ----
        int kp0 = 0, kp1 = 0, kp2 = 0, kp3 = 0;
        #pragma unroll
        for (int p = 0; p < 4; ++p) {          // row = lg*4 + p
            float b = acc[0][p];
            #pragma unroll
            for (int kt = 1; kt < 16; ++kt) b = fmaxf(b, acc[kt][p]);
            b = fmaxf(b, dppf<0xB1>(b));       // quad_perm xor1
            b = fmaxf(b, dppf<0x4E>(b));       // quad_perm xor2
            b = fmaxf(b, dppf<0x141>(b));      // row_half_mirror
            b = fmaxf(b, dppf<0x140>(b));      // row_mirror -> 16-lane max
            const float bthr = b - THRGAP;
            int c = 0, bk = 0x7FFFFFFF;
            #pragma unroll
            for (int kt = 15; kt >= 0; --kt) { // descending: lowest candidate k wins
                bool cand = acc[kt][p] >= bthr;
                c += cand ? 1 : 0;
                bk = cand ? (kt * 16 + lr) : bk;
            }
            c += dppi<0xB1>(c);  bk = min(bk, dppi<0xB1>(bk));
            c += dppi<0x4E>(c);  bk = min(bk, dppi<0x4E>(bk));
            c += dppi<0x141>(c); bk = min(bk, dppi<0x141>(bk));
            c += dppi<0x140>(c); bk = min(bk, dppi<0x140>(bk));
            if (bk > 255) bk = 0;              // all-miss guard (NaN-free data)
            if (p == 0) kp0 = bk; else if (p == 1) kp1 = bk;
            else if (p == 2) kp2 = bk; else kp3 = bk;
            if (lr == 0 && c != 1) {           // tie/near-tie -> exact fp64 pass
                unsigned idx = atomicAdd(cnt, 1u);
                if (idx < cap) list[idx] = ((unsigned)(nb + w * 16 + lg * 4 + p) << 6) | (unsigned)m;
            }
        }

        // ---- write: lane -> row nb+w*16+(lane>>2), chunk lane&3 (values from global cb) ----
        int psel = (lane >> 2) & 3;
        int t0 = (psel & 1) ? kp1 : kp0;
        int t1 = (psel & 1) ? kp3 : kp2;
        int kwin = (psel & 2) ? t1 : t0;
        const float4* src = (const float4*)(cb + ((size_t)m * K_CODES + kwin) * D_DIM);
        float4* dst = (float4*)(out + (size_t)(nb + w * 16 + (lane >> 2)) * ROW_F + m * D_DIM);
        dst[lane & 3] = src[lane & 3];
    }
}

// ===================== kernel 2: exact fp64 fixup (unchanged, proven) ========
__global__ __launch_bounds__(256) void pq_fixup_kernel(
    const float* __restrict__ vecs, const float* __restrict__ cb,
    float* __restrict__ out, const unsigned* __restrict__ meta, unsigned cap)
{
    unsigned cnt = meta[0];
    if (cnt > cap) cnt = cap;
    const unsigned nw  = (gridDim.x * blockDim.x) >> 6;
    const unsigned wid = (blockIdx.x * blockDim.x + threadIdx.x) >> 6;
    const int lane = threadIdx.x & 63;

    for (unsigned e = wid; e < cnt; e += nw) {
        unsigned ent = meta[1 + e];
        const int n = (int)(ent >> 6), m = (int)(ent & 63u);
        const float* vrow = vecs + (size_t)n * ROW_F + m * D_DIM;
        double vd[16];
        #pragma unroll
        for (int d = 0; d < 16; ++d) vd[d] = (double)vrow[d];
        double bs = -1e300; int bi = 0;
        #pragma unroll
        for (int j = 0; j < 4; ++j) {
            int k = lane * 4 + j;
            const float* cp = cb + ((size_t)m * K_CODES + k) * D_DIM;
            double vc = 0.0, c2 = 0.0;
            #pragma unroll
            for (int d = 0; d < 16; ++d) {
                double cd = (double)cp[d];
                vc = fma(vd[d], cd, vc);
                c2 = fma(cd, cd, c2);
            }
            double s = 2.0 * vc - c2;
            if (s > bs) { bs = s; bi = k; }
        }
        #pragma unroll
        for (int off = 32; off; off >>= 1) {
            double so = __shfl_xor(bs, off, 64);
            int    ko = __shfl_xor(bi, off, 64);
            if (so > bs || (so == bs && ko < bi)) { bs = so; bi = ko; }
        }
        if (lane < 4) {
            const float4* src = (const float4*)(cb + ((size_t)m * K_CODES + bi) * D_DIM);
            float4* dst = (float4*)(out + (size_t)n * ROW_F + m * D_DIM);
            dst[lane] = src[lane];
        }
    }
}

extern "C" void kernel_launch(void* const* d_in, const int* in_sizes, int n_in,
                              void* d_out, int out_size, void* d_ws, size_t ws_size,
                              hipStream_t stream) {
    const float* vecs = (const float*)d_in[0];
    const float* cb   = (const float*)d_in[1];
    float* out        = (float*)d_out;
    unsigned* meta    = (unsigned*)d_ws;
    unsigned cap      = (unsigned)(ws_size / 4) - 16;

    hipMemsetAsync(meta, 0, 4, stream);   // zero append counter
    pq_mfma_kernel<<<dim3(8192 / NR, YS), 256, 0, stream>>>(vecs, cb, out, meta, cap);
    pq_fixup_kernel<<<256, 256, 0, stream>>>(vecs, cb, out, meta, cap);
}